// Round 3
// baseline (1016.861 us; speedup 1.0000x reference)
//
#include <hip/hip_runtime.h>

#define NRES 262144
#define BM 16

// LDS map (floats):
//   As  [16][388] @ 0       (LN'd x tile, fp32; stride 388 = 384+4 pad)
//   Ws  [64][132] @ 6208    (weight K-slab)
//   Act [16][132] @ 14656   (act0)
//   A1  [16][132] @ 0       (act1, aliases As -- As dead by then)
#define AS_STRIDE 388
#define WS_STRIDE 132
#define ACT_STRIDE 132
#define WS_OFF 6208
#define ACT_OFF 14656
#define SM_FLOATS 16768   // 67072 bytes -> 2 blocks/CU

__global__ __launch_bounds__(256, 2)
void lddt_fp32(const float* __restrict__ x,
               const float* __restrict__ ln_scale,
               const float* __restrict__ ln_bias,
               const float* __restrict__ w0,
               const float* __restrict__ b0,
               const float* __restrict__ w1,
               const float* __restrict__ b1,
               const float* __restrict__ w2,
               const float* __restrict__ b2,
               float* __restrict__ out) {
    __shared__ __align__(16) float smf[SM_FLOATS];

    const int tid = threadIdx.x;
    const long rowBase = (long)blockIdx.x * BM;

    // ---------------- Phase 1: LayerNorm -> As (fp32) ----------------
    {
        const int row = tid >> 4;          // 0..15, 16 threads per row
        const int j   = tid & 15;
        const long gr = rowBase + row;
        const float4* x4 = (const float4*)x;
        float4 v[6];
#pragma unroll
        for (int cs = 0; cs < 6; ++cs)
            v[cs] = x4[gr * 96 + cs * 16 + j];

        float s = 0.f, sq = 0.f;
#pragma unroll
        for (int cs = 0; cs < 6; ++cs) {
            s  += v[cs].x + v[cs].y + v[cs].z + v[cs].w;
            sq += v[cs].x*v[cs].x + v[cs].y*v[cs].y + v[cs].z*v[cs].z + v[cs].w*v[cs].w;
        }
#pragma unroll
        for (int d = 1; d < 16; d <<= 1) {   // reduce across the 16 lanes sharing a row
            s  += __shfl_xor(s,  d);
            sq += __shfl_xor(sq, d);
        }
        const float mu  = s * (1.0f / 384.0f);
        const float var = sq * (1.0f / 384.0f) - mu * mu;
        const float rs  = rsqrtf(var + 1e-5f);
#pragma unroll
        for (int cs = 0; cs < 6; ++cs) {
            const float4 sc = ((const float4*)ln_scale)[cs * 16 + j];
            const float4 bi = ((const float4*)ln_bias )[cs * 16 + j];
            float4 o;
            o.x = (v[cs].x - mu) * rs * sc.x + bi.x;
            o.y = (v[cs].y - mu) * rs * sc.y + bi.y;
            o.z = (v[cs].z - mu) * rs * sc.z + bi.z;
            o.w = (v[cs].w - mu) * rs * sc.w + bi.w;
            *(float4*)&smf[row * AS_STRIDE + (cs * 16 + j) * 4] = o;
        }
    }

    // Thread tile for GEMM0/GEMM1: rows rg*2..rg*2+1, cols cg*4..cg*4+3
    const int rg = tid >> 5;   // 0..7  -> 16 rows
    const int cg = tid & 31;   // 0..31 -> 128 cols

    // ---------------- GEMM0: [16,384] @ w0[384,128] + b0, ReLU -> Act ----------------
    {
        float acc[2][4];
#pragma unroll
        for (int i = 0; i < 2; ++i)
#pragma unroll
            for (int c = 0; c < 4; ++c) acc[i][c] = 0.f;

        for (int slab = 0; slab < 6; ++slab) {
            __syncthreads();
            for (int i = tid; i < 64 * 128; i += 256) {
                const int kk = i >> 7, c = i & 127;
                smf[WS_OFF + kk * WS_STRIDE + c] = w0[(slab * 64 + kk) * 128 + c];
            }
            __syncthreads();
#pragma unroll 8
            for (int kk = 0; kk < 64; ++kk) {
                float4 wv = *(const float4*)&smf[WS_OFF + kk * WS_STRIDE + cg * 4];
                float av[2];
#pragma unroll
                for (int i = 0; i < 2; ++i)
                    av[i] = smf[(rg * 2 + i) * AS_STRIDE + slab * 64 + kk];
#pragma unroll
                for (int i = 0; i < 2; ++i) {
                    acc[i][0] += av[i] * wv.x;
                    acc[i][1] += av[i] * wv.y;
                    acc[i][2] += av[i] * wv.z;
                    acc[i][3] += av[i] * wv.w;
                }
            }
        }
        __syncthreads();
        const float4 bb = ((const float4*)b0)[cg];
#pragma unroll
        for (int i = 0; i < 2; ++i) {
            float4 o;
            o.x = fmaxf(acc[i][0] + bb.x, 0.f);
            o.y = fmaxf(acc[i][1] + bb.y, 0.f);
            o.z = fmaxf(acc[i][2] + bb.z, 0.f);
            o.w = fmaxf(acc[i][3] + bb.w, 0.f);
            *(float4*)&smf[ACT_OFF + (rg * 2 + i) * ACT_STRIDE + cg * 4] = o;
        }
    }

    // ---------------- GEMM1: [16,128] @ w1[128,128] + b1, ReLU -> A1 (aliases As) ----------------
    {
        float acc[2][4];
#pragma unroll
        for (int i = 0; i < 2; ++i)
#pragma unroll
            for (int c = 0; c < 4; ++c) acc[i][c] = 0.f;

        for (int slab = 0; slab < 2; ++slab) {
            __syncthreads();
            for (int i = tid; i < 64 * 128; i += 256) {
                const int kk = i >> 7, c = i & 127;
                smf[WS_OFF + kk * WS_STRIDE + c] = w1[(slab * 64 + kk) * 128 + c];
            }
            __syncthreads();
#pragma unroll 8
            for (int kk = 0; kk < 64; ++kk) {
                float4 wv = *(const float4*)&smf[WS_OFF + kk * WS_STRIDE + cg * 4];
                float av[2];
#pragma unroll
                for (int i = 0; i < 2; ++i)
                    av[i] = smf[ACT_OFF + (rg * 2 + i) * ACT_STRIDE + slab * 64 + kk];
#pragma unroll
                for (int i = 0; i < 2; ++i) {
                    acc[i][0] += av[i] * wv.x;
                    acc[i][1] += av[i] * wv.y;
                    acc[i][2] += av[i] * wv.z;
                    acc[i][3] += av[i] * wv.w;
                }
            }
        }
        __syncthreads();   // all GEMM1 reads done before A1 overwrites As region
        const float4 bb = ((const float4*)b1)[cg];
#pragma unroll
        for (int i = 0; i < 2; ++i) {
            float4 o;
            o.x = fmaxf(acc[i][0] + bb.x, 0.f);
            o.y = fmaxf(acc[i][1] + bb.y, 0.f);
            o.z = fmaxf(acc[i][2] + bb.z, 0.f);
            o.w = fmaxf(acc[i][3] + bb.w, 0.f);
            *(float4*)&smf[(rg * 2 + i) * ACT_STRIDE + cg * 4] = o;
        }
    }

    // ---------------- GEMM2: [16,128] @ w2[128,50] + b2 -> out ----------------
    {
        const int cg2  = tid & 31;       // 0..31 -> 64 padded cols, 2 per thread
        const int col0 = cg2 * 2;
        float acc[2][2];
#pragma unroll
        for (int i = 0; i < 2; ++i) { acc[i][0] = 0.f; acc[i][1] = 0.f; }

        for (int slab = 0; slab < 2; ++slab) {
            __syncthreads();
            for (int i = tid; i < 64 * 64; i += 256) {
                const int kk = i >> 6, c = i & 63;
                smf[WS_OFF + kk * WS_STRIDE + c] =
                    (c < 50) ? w2[(slab * 64 + kk) * 50 + c] : 0.f;
            }
            __syncthreads();
#pragma unroll 8
            for (int kk = 0; kk < 64; ++kk) {
                const float w2a = smf[WS_OFF + kk * WS_STRIDE + col0];
                const float w2b = smf[WS_OFF + kk * WS_STRIDE + col0 + 1];
#pragma unroll
                for (int i = 0; i < 2; ++i) {
                    const float a = smf[(rg * 2 + i) * ACT_STRIDE + slab * 64 + kk];
                    acc[i][0] += a * w2a;
                    acc[i][1] += a * w2b;
                }
            }
        }
#pragma unroll
        for (int i = 0; i < 2; ++i)
#pragma unroll
            for (int c = 0; c < 2; ++c) {
                const int col = col0 + c;
                if (col < 50) {
                    const long grow = rowBase + rg * 2 + i;
                    out[grow * 50 + col] = acc[i][c] + b2[col];
                }
            }
    }
}

extern "C" void kernel_launch(void* const* d_in, const int* in_sizes, int n_in,
                              void* d_out, int out_size, void* d_ws, size_t ws_size,
                              hipStream_t stream) {
    const float* x        = (const float*)d_in[0];
    const float* ln_scale = (const float*)d_in[1];
    const float* ln_bias  = (const float*)d_in[2];
    const float* w0       = (const float*)d_in[3];
    const float* b0       = (const float*)d_in[4];
    const float* w1       = (const float*)d_in[5];
    const float* b1       = (const float*)d_in[6];
    const float* w2       = (const float*)d_in[7];
    const float* b2       = (const float*)d_in[8];
    float* out = (float*)d_out;

    lddt_fp32<<<NRES / BM, 256, 0, stream>>>(
        x, ln_scale, ln_bias, w0, b0, w1, b1, w2, b2, out);
}

// Round 4
// 480.373 us; speedup vs baseline: 2.1168x; 2.1168x over previous
//
#include <hip/hip_runtime.h>

typedef short bf16x8 __attribute__((ext_vector_type(8)));
typedef float f32x4 __attribute__((ext_vector_type(4)));

#define NRES 262144
#define BM 64

// LDS map (ushort units), total 77824 ushorts = 155,648 B (1 block/CU)
//   A0H [64][392] @ 0        A0L [64][392] @ 25088     (LN'd x, bf16 hi/lo)
//   WSH [128][40] @ 50176    WSL [128][40] @ 55296     (weight slab, bf16 hi/lo)
//   AC0H [64][136] @ 60416   AC0L [64][136] @ 69120    (act0 hi/lo)
//   act1 hi/lo alias A0H/A0L (A0 dead after GEMM0)
#define A0H 0
#define A0L 25088
#define WSH 50176
#define WSL 55296
#define AC0H 60416
#define AC0L 69120
#define SMU 77824
#define A0_STR 392
#define ACT_STR 136
#define WS_STR 40

__device__ __forceinline__ unsigned short f2bf(float f) {
    unsigned u = __builtin_bit_cast(unsigned, f);
    u += 0x7FFFu + ((u >> 16) & 1u);          // round-to-nearest-even
    return (unsigned short)(u >> 16);
}
__device__ __forceinline__ float bf2f(unsigned short h) {
    unsigned u = ((unsigned)h) << 16;
    return __builtin_bit_cast(float, u);
}

__global__ __launch_bounds__(512, 2)
void lddt_mfma(const float* __restrict__ x,
               const float* __restrict__ ln_scale,
               const float* __restrict__ ln_bias,
               const float* __restrict__ w0,
               const float* __restrict__ b0,
               const float* __restrict__ w1,
               const float* __restrict__ b1,
               const float* __restrict__ w2,
               const float* __restrict__ b2,
               float* __restrict__ out) {
    __shared__ __align__(16) unsigned short sm[SMU];

    const int tid  = threadIdx.x;
    const int lane = tid & 63;
    const int l15  = lane & 15;
    const int lg   = lane >> 4;          // 0..3
    const int wid  = tid >> 6;           // 0..7
    const int wm   = wid >> 2;           // 0..1  row half (32 rows)
    const int wn   = wid & 3;            // 0..3  col quarter (32 cols)
    const long rowBase = (long)blockIdx.x * BM;

    // ---------------- Phase 1: LayerNorm -> A0 hi/lo (verified round-3 pattern) ----------------
    {
        const float4* x4 = (const float4*)x;
        const int j = tid & 15;
#pragma unroll
        for (int rep = 0; rep < 2; ++rep) {
            const int row = rep * 32 + (tid >> 4);    // 16 threads per row
            const long gr = rowBase + row;
            float4 v[6];
#pragma unroll
            for (int cs = 0; cs < 6; ++cs)
                v[cs] = x4[gr * 96 + cs * 16 + j];

            float s = 0.f, sq = 0.f;
#pragma unroll
            for (int cs = 0; cs < 6; ++cs) {
                s  += v[cs].x + v[cs].y + v[cs].z + v[cs].w;
                sq += v[cs].x*v[cs].x + v[cs].y*v[cs].y + v[cs].z*v[cs].z + v[cs].w*v[cs].w;
            }
#pragma unroll
            for (int d = 1; d < 16; d <<= 1) {        // reduce across the row's 16 lanes
                s  += __shfl_xor(s,  d);
                sq += __shfl_xor(sq, d);
            }
            const float mu  = s * (1.0f / 384.0f);
            const float var = sq * (1.0f / 384.0f) - mu * mu;
            const float rs  = rsqrtf(var + 1e-5f);
#pragma unroll
            for (int cs = 0; cs < 6; ++cs) {
                const float4 sc = ((const float4*)ln_scale)[cs * 16 + j];
                const float4 bi = ((const float4*)ln_bias )[cs * 16 + j];
                float f[4];
                f[0] = (v[cs].x - mu) * rs * sc.x + bi.x;
                f[1] = (v[cs].y - mu) * rs * sc.y + bi.y;
                f[2] = (v[cs].z - mu) * rs * sc.z + bi.z;
                f[3] = (v[cs].w - mu) * rs * sc.w + bi.w;
                union { unsigned short h[4]; uint2 u; } ph, pl;
#pragma unroll
                for (int e = 0; e < 4; ++e) {
                    ph.h[e] = f2bf(f[e]);
                    pl.h[e] = f2bf(f[e] - bf2f(ph.h[e]));
                }
                const int base = row * A0_STR + cs * 64 + j * 4;
                *(uint2*)&sm[A0H + base] = ph.u;
                *(uint2*)&sm[A0L + base] = pl.u;
            }
        }
    }

    // ---------------- GEMM0: [64,384] @ w0[384,128] + b0, ReLU -> act0 hi/lo ----------------
    {
        f32x4 acc[2][2];
#pragma unroll
        for (int m = 0; m < 2; ++m) { acc[m][0] = (f32x4)0.0f; acc[m][1] = (f32x4)0.0f; }

        for (int s = 0; s < 12; ++s) {
            __syncthreads();
#pragma unroll
            for (int t = 0; t < 8; ++t) {            // stage slab: 4096 elems, 8/thread
                const int i = tid + t * 512;
                const int col = i & 127, kk = i >> 7;
                const float wv = w0[(s * 32 + kk) * 128 + col];
                const unsigned short h = f2bf(wv);
                sm[WSH + col * WS_STR + kk] = h;
                sm[WSL + col * WS_STR + kk] = f2bf(wv - bf2f(h));
            }
            __syncthreads();
            bf16x8 ah[2], al[2], bh[2], bl[2];
#pragma unroll
            for (int m = 0; m < 2; ++m) {
                const int arow = wm * 32 + m * 16 + l15;
                ah[m] = *(const bf16x8*)&sm[A0H + arow * A0_STR + s * 32 + lg * 8];
                al[m] = *(const bf16x8*)&sm[A0L + arow * A0_STR + s * 32 + lg * 8];
            }
#pragma unroll
            for (int n = 0; n < 2; ++n) {
                const int bcol = wn * 32 + n * 16 + l15;
                bh[n] = *(const bf16x8*)&sm[WSH + bcol * WS_STR + lg * 8];
                bl[n] = *(const bf16x8*)&sm[WSL + bcol * WS_STR + lg * 8];
            }
#pragma unroll
            for (int m = 0; m < 2; ++m)
#pragma unroll
                for (int n = 0; n < 2; ++n) {
                    acc[m][n] = __builtin_amdgcn_mfma_f32_16x16x32_bf16(ah[m], bh[n], acc[m][n], 0, 0, 0);
                    acc[m][n] = __builtin_amdgcn_mfma_f32_16x16x32_bf16(ah[m], bl[n], acc[m][n], 0, 0, 0);
                    acc[m][n] = __builtin_amdgcn_mfma_f32_16x16x32_bf16(al[m], bh[n], acc[m][n], 0, 0, 0);
                }
        }
#pragma unroll
        for (int m = 0; m < 2; ++m)
#pragma unroll
            for (int n = 0; n < 2; ++n) {
                const int col = wn * 32 + n * 16 + l15;
                const float bb = b0[col];
#pragma unroll
                for (int r = 0; r < 4; ++r) {
                    const int row = wm * 32 + m * 16 + lg * 4 + r;
                    const float z = fmaxf(acc[m][n][r] + bb, 0.0f);
                    const unsigned short h = f2bf(z);
                    sm[AC0H + row * ACT_STR + col] = h;
                    sm[AC0L + row * ACT_STR + col] = f2bf(z - bf2f(h));
                }
            }
    }

    // ---------------- GEMM1: [64,128] @ w1[128,128] + b1, ReLU -> act1 hi/lo (alias A0) ----------------
    {
        f32x4 acc[2][2];
#pragma unroll
        for (int m = 0; m < 2; ++m) { acc[m][0] = (f32x4)0.0f; acc[m][1] = (f32x4)0.0f; }

        for (int s = 0; s < 4; ++s) {
            __syncthreads();                         // also orders act0 writes -> reads (s==0)
#pragma unroll
            for (int t = 0; t < 8; ++t) {
                const int i = tid + t * 512;
                const int col = i & 127, kk = i >> 7;
                const float wv = w1[(s * 32 + kk) * 128 + col];
                const unsigned short h = f2bf(wv);
                sm[WSH + col * WS_STR + kk] = h;
                sm[WSL + col * WS_STR + kk] = f2bf(wv - bf2f(h));
            }
            __syncthreads();
            bf16x8 ah[2], al[2], bh[2], bl[2];
#pragma unroll
            for (int m = 0; m < 2; ++m) {
                const int arow = wm * 32 + m * 16 + l15;
                ah[m] = *(const bf16x8*)&sm[AC0H + arow * ACT_STR + s * 32 + lg * 8];
                al[m] = *(const bf16x8*)&sm[AC0L + arow * ACT_STR + s * 32 + lg * 8];
            }
#pragma unroll
            for (int n = 0; n < 2; ++n) {
                const int bcol = wn * 32 + n * 16 + l15;
                bh[n] = *(const bf16x8*)&sm[WSH + bcol * WS_STR + lg * 8];
                bl[n] = *(const bf16x8*)&sm[WSL + bcol * WS_STR + lg * 8];
            }
#pragma unroll
            for (int m = 0; m < 2; ++m)
#pragma unroll
                for (int n = 0; n < 2; ++n) {
                    acc[m][n] = __builtin_amdgcn_mfma_f32_16x16x32_bf16(ah[m], bh[n], acc[m][n], 0, 0, 0);
                    acc[m][n] = __builtin_amdgcn_mfma_f32_16x16x32_bf16(ah[m], bl[n], acc[m][n], 0, 0, 0);
                    acc[m][n] = __builtin_amdgcn_mfma_f32_16x16x32_bf16(al[m], bh[n], acc[m][n], 0, 0, 0);
                }
        }
        // act1 (alias A0, dead since GEMM0) -- write region disjoint from AC0/WS reads
#pragma unroll
        for (int m = 0; m < 2; ++m)
#pragma unroll
            for (int n = 0; n < 2; ++n) {
                const int col = wn * 32 + n * 16 + l15;
                const float bb = b1[col];
#pragma unroll
                for (int r = 0; r < 4; ++r) {
                    const int row = wm * 32 + m * 16 + lg * 4 + r;
                    const float z = fmaxf(acc[m][n][r] + bb, 0.0f);
                    const unsigned short h = f2bf(z);
                    sm[A0H + row * ACT_STR + col] = h;
                    sm[A0L + row * ACT_STR + col] = f2bf(z - bf2f(h));
                }
            }
    }

    // ---------------- GEMM2: [64,128] @ w2[128,50->64] + b2 -> out ----------------
    {
        f32x4 acc[2];
        acc[0] = (f32x4)0.0f; acc[1] = (f32x4)0.0f;

        for (int s = 0; s < 4; ++s) {
            __syncthreads();                         // orders act1 writes / w1 reads vs w2 stage
#pragma unroll
            for (int t = 0; t < 4; ++t) {            // stage slab: 64x32 = 2048 elems
                const int i = tid + t * 512;
                const int col = i & 63, kk = i >> 6;
                const float wv = (col < 50) ? w2[(s * 32 + kk) * 50 + col] : 0.0f;
                const unsigned short h = f2bf(wv);
                sm[WSH + col * WS_STR + kk] = h;
                sm[WSL + col * WS_STR + kk] = f2bf(wv - bf2f(h));
            }
            __syncthreads();
            bf16x8 ah[2], al[2], bh, bl;
#pragma unroll
            for (int m = 0; m < 2; ++m) {
                const int arow = wm * 32 + m * 16 + l15;
                ah[m] = *(const bf16x8*)&sm[A0H + arow * ACT_STR + s * 32 + lg * 8];
                al[m] = *(const bf16x8*)&sm[A0L + arow * ACT_STR + s * 32 + lg * 8];
            }
            {
                const int bcol = wn * 16 + l15;      // 4 waves x 16 = 64 padded cols
                bh = *(const bf16x8*)&sm[WSH + bcol * WS_STR + lg * 8];
                bl = *(const bf16x8*)&sm[WSL + bcol * WS_STR + lg * 8];
            }
#pragma unroll
            for (int m = 0; m < 2; ++m) {
                acc[m] = __builtin_amdgcn_mfma_f32_16x16x32_bf16(ah[m], bh, acc[m], 0, 0, 0);
                acc[m] = __builtin_amdgcn_mfma_f32_16x16x32_bf16(ah[m], bl, acc[m], 0, 0, 0);
                acc[m] = __builtin_amdgcn_mfma_f32_16x16x32_bf16(al[m], bh, acc[m], 0, 0, 0);
            }
        }
        const int col = wn * 16 + l15;
        if (col < 50) {
            const float bb = b2[col];
#pragma unroll
            for (int m = 0; m < 2; ++m)
#pragma unroll
                for (int r = 0; r < 4; ++r) {
                    const long row = rowBase + wm * 32 + m * 16 + lg * 4 + r;
                    out[row * 50 + col] = acc[m][r] + bb;
                }
        }
    }
}

extern "C" void kernel_launch(void* const* d_in, const int* in_sizes, int n_in,
                              void* d_out, int out_size, void* d_ws, size_t ws_size,
                              hipStream_t stream) {
    const float* x        = (const float*)d_in[0];
    const float* ln_scale = (const float*)d_in[1];
    const float* ln_bias  = (const float*)d_in[2];
    const float* w0       = (const float*)d_in[3];
    const float* b0       = (const float*)d_in[4];
    const float* w1       = (const float*)d_in[5];
    const float* b1       = (const float*)d_in[6];
    const float* w2       = (const float*)d_in[7];
    const float* b2       = (const float*)d_in[8];
    float* out = (float*)d_out;

    lddt_mfma<<<NRES / BM, 512, 0, stream>>>(
        x, ln_scale, ln_bias, w0, b0, w1, b1, w2, b2, out);
}

// Round 7
// 373.748 us; speedup vs baseline: 2.7207x; 1.2853x over previous
//
#include <hip/hip_runtime.h>

typedef short bf16x8 __attribute__((ext_vector_type(8)));
typedef float f32x4 __attribute__((ext_vector_type(4)));

#define NRES 262144
#define BM 32

// LDS (u16 units), padded strides (R4-proven), 67,584 B -> 2 blocks/CU:
//   A0H [32][392] @ 0       A0L @ 12544     (LN'd x, bf16 hi/lo)
//   AC0H [32][136] @ 25088  AC0L @ 29440    (act0 hi/lo)
//   act1 hi/lo alias A0 region (A0 dead after GEMM0)
#define A0H 0
#define A0L 12544
#define AC0H 25088
#define AC0L 29440
#define A1H 0
#define A1L 12544
#define SMU 33792
#define A0_STR 392
#define ACT_STR 136

__device__ __forceinline__ unsigned short f2bf(float f) {
    unsigned u = __builtin_bit_cast(unsigned, f);
    u += 0x7FFFu + ((u >> 16) & 1u);          // round-to-nearest-even
    return (unsigned short)(u >> 16);
}
__device__ __forceinline__ float bf2f(unsigned short h) {
    unsigned u = ((unsigned)h) << 16;
    return __builtin_bit_cast(float, u);
}

// Build B-fragment pair (hi,lo) in registers from fp32 weights in global.
// w[(k0+j)*ldw + col], j=0..7.  16 l15-lanes hit consecutive cols -> 64B segments.
__device__ __forceinline__ void bfrag(const float* __restrict__ w, int ldw, int col, int k0,
                                      bf16x8& bh, bf16x8& bl) {
    union { unsigned u[4]; bf16x8 v; } H, L;
#pragma unroll
    for (int jj = 0; jj < 4; ++jj) {
        const float f0 = w[(k0 + 2 * jj)     * ldw + col];
        const float f1 = w[(k0 + 2 * jj + 1) * ldw + col];
        const unsigned short h0 = f2bf(f0), h1 = f2bf(f1);
        const unsigned short l0 = f2bf(f0 - bf2f(h0)), l1 = f2bf(f1 - bf2f(h1));
        H.u[jj] = (unsigned)h0 | ((unsigned)h1 << 16);
        L.u[jj] = (unsigned)l0 | ((unsigned)l1 << 16);
    }
    bh = H.v; bl = L.v;
}
// w2 variant: ldw=50, cols >= 50 read as zero.
__device__ __forceinline__ void bfrag50(const float* __restrict__ w, int col, int k0,
                                        bf16x8& bh, bf16x8& bl) {
    union { unsigned u[4]; bf16x8 v; } H, L;
    const bool ok = (col < 50);
#pragma unroll
    for (int jj = 0; jj < 4; ++jj) {
        const float f0 = ok ? w[(k0 + 2 * jj)     * 50 + col] : 0.0f;
        const float f1 = ok ? w[(k0 + 2 * jj + 1) * 50 + col] : 0.0f;
        const unsigned short h0 = f2bf(f0), h1 = f2bf(f1);
        const unsigned short l0 = f2bf(f0 - bf2f(h0)), l1 = f2bf(f1 - bf2f(h1));
        H.u[jj] = (unsigned)h0 | ((unsigned)h1 << 16);
        L.u[jj] = (unsigned)l0 | ((unsigned)l1 << 16);
    }
    bh = H.v; bl = L.v;
}

__global__ __launch_bounds__(256, 2)
void lddt_mfma(const float* __restrict__ x,
               const float* __restrict__ ln_scale,
               const float* __restrict__ ln_bias,
               const float* __restrict__ w0,
               const float* __restrict__ b0,
               const float* __restrict__ w1,
               const float* __restrict__ b1,
               const float* __restrict__ w2,
               const float* __restrict__ b2,
               float* __restrict__ out) {
    __shared__ __align__(16) unsigned short sm[SMU];

    const int tid  = threadIdx.x;
    const int lane = tid & 63;
    const int l15  = lane & 15;
    const int lg   = lane >> 4;          // 0..3
    const int wid  = tid >> 6;           // 0..3 (wave = output-col quarter)
    const long rowBase = (long)blockIdx.x * BM;

    // ---------------- Phase 1: LayerNorm -> A0 hi/lo (padded LDS) ----------------
    {
        const float4* x4 = (const float4*)x;
        const int j = tid & 15;
#pragma unroll
        for (int rep = 0; rep < 2; ++rep) {
            const int row = rep * 16 + (tid >> 4);    // 16 threads per row
            const long gr = rowBase + row;
            float4 v[6];
#pragma unroll
            for (int cs = 0; cs < 6; ++cs)
                v[cs] = x4[gr * 96 + cs * 16 + j];

            float s = 0.f, sq = 0.f;
#pragma unroll
            for (int cs = 0; cs < 6; ++cs) {
                s  += v[cs].x + v[cs].y + v[cs].z + v[cs].w;
                sq += v[cs].x*v[cs].x + v[cs].y*v[cs].y + v[cs].z*v[cs].z + v[cs].w*v[cs].w;
            }
#pragma unroll
            for (int d = 1; d < 16; d <<= 1) {
                s  += __shfl_xor(s,  d);
                sq += __shfl_xor(sq, d);
            }
            const float mu  = s * (1.0f / 384.0f);
            const float var = sq * (1.0f / 384.0f) - mu * mu;
            const float rs  = rsqrtf(var + 1e-5f);
#pragma unroll
            for (int cs = 0; cs < 6; ++cs) {
                const float4 sc = ((const float4*)ln_scale)[cs * 16 + j];
                const float4 bi = ((const float4*)ln_bias )[cs * 16 + j];
                float f[4];
                f[0] = (v[cs].x - mu) * rs * sc.x + bi.x;
                f[1] = (v[cs].y - mu) * rs * sc.y + bi.y;
                f[2] = (v[cs].z - mu) * rs * sc.z + bi.z;
                f[3] = (v[cs].w - mu) * rs * sc.w + bi.w;
                union { unsigned short h[4]; uint2 u; } ph, pl;
#pragma unroll
                for (int e = 0; e < 4; ++e) {
                    ph.h[e] = f2bf(f[e]);
                    pl.h[e] = f2bf(f[e] - bf2f(ph.h[e]));
                }
                const int idx = row * A0_STR + cs * 64 + j * 4;
                *(uint2*)&sm[A0H + idx] = ph.u;
                *(uint2*)&sm[A0L + idx] = pl.u;
            }
        }
    }
    __syncthreads();

    // ---------------- GEMM0: [32,384] @ w0[384,128] + b0, ReLU -> act0 ----------------
    {
        f32x4 acc[2][2];
#pragma unroll
        for (int m = 0; m < 2; ++m) { acc[m][0] = (f32x4)0.0f; acc[m][1] = (f32x4)0.0f; }

#pragma unroll 4
        for (int s = 0; s < 12; ++s) {
            bf16x8 bh[2], bl[2], ah[2], al[2];
#pragma unroll
            for (int n = 0; n < 2; ++n)
                bfrag(w0, 128, wid * 32 + n * 16 + l15, s * 32 + lg * 8, bh[n], bl[n]);
#pragma unroll
            for (int m = 0; m < 2; ++m) {
                const int idx = (m * 16 + l15) * A0_STR + s * 32 + lg * 8;
                ah[m] = *(const bf16x8*)&sm[A0H + idx];
                al[m] = *(const bf16x8*)&sm[A0L + idx];
            }
#pragma unroll
            for (int m = 0; m < 2; ++m)
#pragma unroll
                for (int n = 0; n < 2; ++n) {
                    acc[m][n] = __builtin_amdgcn_mfma_f32_16x16x32_bf16(ah[m], bh[n], acc[m][n], 0, 0, 0);
                    acc[m][n] = __builtin_amdgcn_mfma_f32_16x16x32_bf16(ah[m], bl[n], acc[m][n], 0, 0, 0);
                    acc[m][n] = __builtin_amdgcn_mfma_f32_16x16x32_bf16(al[m], bh[n], acc[m][n], 0, 0, 0);
                }
        }
#pragma unroll
        for (int m = 0; m < 2; ++m)
#pragma unroll
            for (int n = 0; n < 2; ++n) {
                const int col = wid * 32 + n * 16 + l15;
                const float bb = b0[col];
#pragma unroll
                for (int r = 0; r < 4; ++r) {
                    const int row = m * 16 + lg * 4 + r;
                    const float z = fmaxf(acc[m][n][r] + bb, 0.0f);
                    const unsigned short h = f2bf(z);
                    const int idx = row * ACT_STR + col;
                    sm[AC0H + idx] = h;
                    sm[AC0L + idx] = f2bf(z - bf2f(h));
                }
            }
    }
    __syncthreads();

    // ---------------- GEMM1: [32,128] @ w1[128,128] + b1, ReLU -> act1 (alias A0) ----------------
    {
        f32x4 acc[2][2];
#pragma unroll
        for (int m = 0; m < 2; ++m) { acc[m][0] = (f32x4)0.0f; acc[m][1] = (f32x4)0.0f; }

#pragma unroll
        for (int s = 0; s < 4; ++s) {
            bf16x8 bh[2], bl[2], ah[2], al[2];
#pragma unroll
            for (int n = 0; n < 2; ++n)
                bfrag(w1, 128, wid * 32 + n * 16 + l15, s * 32 + lg * 8, bh[n], bl[n]);
#pragma unroll
            for (int m = 0; m < 2; ++m) {
                const int idx = (m * 16 + l15) * ACT_STR + s * 32 + lg * 8;
                ah[m] = *(const bf16x8*)&sm[AC0H + idx];
                al[m] = *(const bf16x8*)&sm[AC0L + idx];
            }
#pragma unroll
            for (int m = 0; m < 2; ++m)
#pragma unroll
                for (int n = 0; n < 2; ++n) {
                    acc[m][n] = __builtin_amdgcn_mfma_f32_16x16x32_bf16(ah[m], bh[n], acc[m][n], 0, 0, 0);
                    acc[m][n] = __builtin_amdgcn_mfma_f32_16x16x32_bf16(ah[m], bl[n], acc[m][n], 0, 0, 0);
                    acc[m][n] = __builtin_amdgcn_mfma_f32_16x16x32_bf16(al[m], bh[n], acc[m][n], 0, 0, 0);
                }
        }
#pragma unroll
        for (int m = 0; m < 2; ++m)
#pragma unroll
            for (int n = 0; n < 2; ++n) {
                const int col = wid * 32 + n * 16 + l15;
                const float bb = b1[col];
#pragma unroll
                for (int r = 0; r < 4; ++r) {
                    const int row = m * 16 + lg * 4 + r;
                    const float z = fmaxf(acc[m][n][r] + bb, 0.0f);
                    const unsigned short h = f2bf(z);
                    const int idx = row * ACT_STR + col;
                    sm[A1H + idx] = h;
                    sm[A1L + idx] = f2bf(z - bf2f(h));
                }
            }
    }
    __syncthreads();

    // ---------------- GEMM2: [32,128] @ w2[128,50->64] + b2 -> out ----------------
    {
        f32x4 acc[2];
        acc[0] = (f32x4)0.0f; acc[1] = (f32x4)0.0f;
        const int bcol = wid * 16 + l15;             // 4 waves x 16 = 64 padded cols

#pragma unroll
        for (int s = 0; s < 4; ++s) {
            bf16x8 bh, bl, ah[2], al[2];
            bfrag50(w2, bcol, s * 32 + lg * 8, bh, bl);
#pragma unroll
            for (int m = 0; m < 2; ++m) {
                const int idx = (m * 16 + l15) * ACT_STR + s * 32 + lg * 8;
                ah[m] = *(const bf16x8*)&sm[A1H + idx];
                al[m] = *(const bf16x8*)&sm[A1L + idx];
            }
#pragma unroll
            for (int m = 0; m < 2; ++m) {
                acc[m] = __builtin_amdgcn_mfma_f32_16x16x32_bf16(ah[m], bh, acc[m], 0, 0, 0);
                acc[m] = __builtin_amdgcn_mfma_f32_16x16x32_bf16(ah[m], bl, acc[m], 0, 0, 0);
                acc[m] = __builtin_amdgcn_mfma_f32_16x16x32_bf16(al[m], bh, acc[m], 0, 0, 0);
            }
        }
        if (bcol < 50) {
            const float bb = b2[bcol];
#pragma unroll
            for (int m = 0; m < 2; ++m)
#pragma unroll
                for (int r = 0; r < 4; ++r) {
                    const long row = rowBase + m * 16 + lg * 4 + r;
                    out[row * 50 + bcol] = acc[m][r] + bb;
                }
        }
    }
}

extern "C" void kernel_launch(void* const* d_in, const int* in_sizes, int n_in,
                              void* d_out, int out_size, void* d_ws, size_t ws_size,
                              hipStream_t stream) {
    const float* x        = (const float*)d_in[0];
    const float* ln_scale = (const float*)d_in[1];
    const float* ln_bias  = (const float*)d_in[2];
    const float* w0       = (const float*)d_in[3];
    const float* b0       = (const float*)d_in[4];
    const float* w1       = (const float*)d_in[5];
    const float* b1       = (const float*)d_in[6];
    const float* w2       = (const float*)d_in[7];
    const float* b2       = (const float*)d_in[8];
    float* out = (float*)d_out;

    lddt_mfma<<<NRES / BM, 256, 0, stream>>>(
        x, ln_scale, ln_bias, w0, b0, w1, b1, w2, b2, out);
}

// Round 11
// 346.674 us; speedup vs baseline: 2.9332x; 1.0781x over previous
//
#include <hip/hip_runtime.h>

typedef short bf16x8 __attribute__((ext_vector_type(8)));
typedef float f32x4 __attribute__((ext_vector_type(4)));

#define NRES 262144
#define BM 32
#define GOODMAGIC 0x600DF00Du

// ws layout: u32 flag @ byte 0 (16B slot), then weights (u16 units, rel. to wt = ws_u16 + 8):
//   WT0H [128c][384k] @ 0      WT0L @ 49152
//   WT1H [128c][128k] @ 98304  WT1L @ 114688
//   WT2H [ 64c][128k] @ 131072 WT2L @ 139264   (cols 50..63 zero)
#define WT0H 0
#define WT0L 49152
#define WT1H 98304
#define WT1L 114688
#define WT2H 131072
#define WT2L 139264
#define PREP_N 73728
#define WS_NEED ((size_t)(16 + PREP_N * 2 * 2))   // 294,928 B

// LDS (u16 units), padded strides (R4/R7-proven), 67,584 B -> 2 blocks/CU
#define A0H 0
#define A0L 12544
#define AC0H 25088
#define AC0L 29440
#define A1H 0
#define A1L 12544
#define SMU 33792
#define A0_STR 392
#define ACT_STR 136

__device__ __forceinline__ unsigned short f2bf(float f) {
    unsigned u = __builtin_bit_cast(unsigned, f);
    u += 0x7FFFu + ((u >> 16) & 1u);          // round-to-nearest-even
    return (unsigned short)(u >> 16);
}
__device__ __forceinline__ float bf2f(unsigned short h) {
    unsigned u = ((unsigned)h) << 16;
    return __builtin_bit_cast(float, u);
}

// ---------------- ws path: flag init, prep, full bit-exact check ----------------
__global__ void set_flag(unsigned* flag, unsigned v) {
    if (threadIdx.x == 0 && blockIdx.x == 0) *flag = v;
}

__device__ __forceinline__ void prep_index(int i, const float* w0, const float* w1,
                                           const float* w2, float& v, int& hi_off, int& lo_off) {
    if (i < 49152) {                        // WT0[col][k] = w0[k][col]
        int col = i / 384, k = i % 384;
        v = w0[k * 128 + col]; hi_off = WT0H + i; lo_off = WT0L + i;
    } else if (i < 65536) {                 // WT1[col][k] = w1[k][col]
        int j = i - 49152; int col = j / 128, k = j % 128;
        v = w1[k * 128 + col]; hi_off = WT1H + j; lo_off = WT1L + j;
    } else {                                // WT2[col][k] = w2[k][col], pad col>=50
        int j = i - 65536; int col = j / 128, k = j % 128;
        v = (col < 50) ? w2[k * 50 + col] : 0.0f; hi_off = WT2H + j; lo_off = WT2L + j;
    }
}

__global__ void prep_weights(const float* __restrict__ w0, const float* __restrict__ w1,
                             const float* __restrict__ w2, unsigned short* __restrict__ wt) {
    const int i = blockIdx.x * blockDim.x + threadIdx.x;
    if (i >= PREP_N) return;
    float v; int hi_off, lo_off;
    prep_index(i, w0, w1, w2, v, hi_off, lo_off);
    const unsigned short h = f2bf(v);
    wt[hi_off] = h;
    wt[lo_off] = f2bf(v - bf2f(h));
}

__global__ void check_weights(const float* __restrict__ w0, const float* __restrict__ w1,
                              const float* __restrict__ w2, const unsigned short* __restrict__ wt,
                              unsigned* flag) {
    const int i = blockIdx.x * blockDim.x + threadIdx.x;
    if (i >= PREP_N) return;
    float v; int hi_off, lo_off;
    prep_index(i, w0, w1, w2, v, hi_off, lo_off);
    const unsigned short h = f2bf(v);
    const unsigned short l = f2bf(v - bf2f(h));
    if (wt[hi_off] != h || wt[lo_off] != l) atomicExch(flag, 0xBAD0BAD0u);
}

// ---------------- shared LayerNorm phase (R7 verbatim) ----------------
__device__ __forceinline__ void ln_phase(const float* __restrict__ x,
                                         const float* __restrict__ ln_scale,
                                         const float* __restrict__ ln_bias,
                                         unsigned short* sm, int tid, long rowBase) {
    const float4* x4 = (const float4*)x;
    const int j = tid & 15;
#pragma unroll
    for (int rep = 0; rep < 2; ++rep) {
        const int row = rep * 16 + (tid >> 4);    // 16 threads per row
        const long gr = rowBase + row;
        float4 v[6];
#pragma unroll
        for (int cs = 0; cs < 6; ++cs)
            v[cs] = x4[gr * 96 + cs * 16 + j];

        float s = 0.f, sq = 0.f;
#pragma unroll
        for (int cs = 0; cs < 6; ++cs) {
            s  += v[cs].x + v[cs].y + v[cs].z + v[cs].w;
            sq += v[cs].x*v[cs].x + v[cs].y*v[cs].y + v[cs].z*v[cs].z + v[cs].w*v[cs].w;
        }
#pragma unroll
        for (int d = 1; d < 16; d <<= 1) {
            s  += __shfl_xor(s,  d);
            sq += __shfl_xor(sq, d);
        }
        const float mu  = s * (1.0f / 384.0f);
        const float var = sq * (1.0f / 384.0f) - mu * mu;
        const float rs  = rsqrtf(var + 1e-5f);
#pragma unroll
        for (int cs = 0; cs < 6; ++cs) {
            const float4 sc = ((const float4*)ln_scale)[cs * 16 + j];
            const float4 bi = ((const float4*)ln_bias )[cs * 16 + j];
            float f[4];
            f[0] = (v[cs].x - mu) * rs * sc.x + bi.x;
            f[1] = (v[cs].y - mu) * rs * sc.y + bi.y;
            f[2] = (v[cs].z - mu) * rs * sc.z + bi.z;
            f[3] = (v[cs].w - mu) * rs * sc.w + bi.w;
            union { unsigned short h[4]; uint2 u; } ph, pl;
#pragma unroll
            for (int e = 0; e < 4; ++e) {
                ph.h[e] = f2bf(f[e]);
                pl.h[e] = f2bf(f[e] - bf2f(ph.h[e]));
            }
            const int idx = row * A0_STR + cs * 64 + j * 4;
            *(uint2*)&sm[A0H + idx] = ph.u;
            *(uint2*)&sm[A0L + idx] = pl.u;
        }
    }
}

// ---------------- fast kernel: weights pre-split in ws ----------------
__global__ __launch_bounds__(256, 2)
void lddt_ws(const float* __restrict__ x,
             const float* __restrict__ ln_scale,
             const float* __restrict__ ln_bias,
             const unsigned short* __restrict__ wt,
             const unsigned* __restrict__ flag,
             const float* __restrict__ b0,
             const float* __restrict__ b1,
             const float* __restrict__ b2,
             float* __restrict__ out) {
    if (*flag != GOODMAGIC) return;           // uniform early exit -> fallback kernel runs

    __shared__ __align__(16) unsigned short sm[SMU];
    const int tid  = threadIdx.x;
    const int lane = tid & 63;
    const int l15  = lane & 15;
    const int lg   = lane >> 4;
    const int wid  = tid >> 6;
    const long rowBase = (long)blockIdx.x * BM;

    ln_phase(x, ln_scale, ln_bias, sm, tid, rowBase);
    __syncthreads();

    // GEMM0
    {
        f32x4 acc[2][2];
#pragma unroll
        for (int m = 0; m < 2; ++m) { acc[m][0] = (f32x4)0.0f; acc[m][1] = (f32x4)0.0f; }
#pragma unroll
        for (int s = 0; s < 12; ++s) {
            bf16x8 bh[2], bl[2], ah[2], al[2];
#pragma unroll
            for (int n = 0; n < 2; ++n) {
                const int bcol = wid * 32 + n * 16 + l15;
                bh[n] = *(const bf16x8*)&wt[WT0H + bcol * 384 + s * 32 + lg * 8];
                bl[n] = *(const bf16x8*)&wt[WT0L + bcol * 384 + s * 32 + lg * 8];
            }
#pragma unroll
            for (int m = 0; m < 2; ++m) {
                const int idx = (m * 16 + l15) * A0_STR + s * 32 + lg * 8;
                ah[m] = *(const bf16x8*)&sm[A0H + idx];
                al[m] = *(const bf16x8*)&sm[A0L + idx];
            }
#pragma unroll
            for (int m = 0; m < 2; ++m)
#pragma unroll
                for (int n = 0; n < 2; ++n) {
                    acc[m][n] = __builtin_amdgcn_mfma_f32_16x16x32_bf16(ah[m], bh[n], acc[m][n], 0, 0, 0);
                    acc[m][n] = __builtin_amdgcn_mfma_f32_16x16x32_bf16(ah[m], bl[n], acc[m][n], 0, 0, 0);
                    acc[m][n] = __builtin_amdgcn_mfma_f32_16x16x32_bf16(al[m], bh[n], acc[m][n], 0, 0, 0);
                }
        }
#pragma unroll
        for (int m = 0; m < 2; ++m)
#pragma unroll
            for (int n = 0; n < 2; ++n) {
                const int col = wid * 32 + n * 16 + l15;
                const float bb = b0[col];
#pragma unroll
                for (int r = 0; r < 4; ++r) {
                    const int row = m * 16 + lg * 4 + r;
                    const float z = fmaxf(acc[m][n][r] + bb, 0.0f);
                    const unsigned short h = f2bf(z);
                    const int idx = row * ACT_STR + col;
                    sm[AC0H + idx] = h;
                    sm[AC0L + idx] = f2bf(z - bf2f(h));
                }
            }
    }
    __syncthreads();

    // GEMM1
    {
        f32x4 acc[2][2];
#pragma unroll
        for (int m = 0; m < 2; ++m) { acc[m][0] = (f32x4)0.0f; acc[m][1] = (f32x4)0.0f; }
#pragma unroll
        for (int s = 0; s < 4; ++s) {
            bf16x8 bh[2], bl[2], ah[2], al[2];
#pragma unroll
            for (int n = 0; n < 2; ++n) {
                const int bcol = wid * 32 + n * 16 + l15;
                bh[n] = *(const bf16x8*)&wt[WT1H + bcol * 128 + s * 32 + lg * 8];
                bl[n] = *(const bf16x8*)&wt[WT1L + bcol * 128 + s * 32 + lg * 8];
            }
#pragma unroll
            for (int m = 0; m < 2; ++m) {
                const int idx = (m * 16 + l15) * ACT_STR + s * 32 + lg * 8;
                ah[m] = *(const bf16x8*)&sm[AC0H + idx];
                al[m] = *(const bf16x8*)&sm[AC0L + idx];
            }
#pragma unroll
            for (int m = 0; m < 2; ++m)
#pragma unroll
                for (int n = 0; n < 2; ++n) {
                    acc[m][n] = __builtin_amdgcn_mfma_f32_16x16x32_bf16(ah[m], bh[n], acc[m][n], 0, 0, 0);
                    acc[m][n] = __builtin_amdgcn_mfma_f32_16x16x32_bf16(ah[m], bl[n], acc[m][n], 0, 0, 0);
                    acc[m][n] = __builtin_amdgcn_mfma_f32_16x16x32_bf16(al[m], bh[n], acc[m][n], 0, 0, 0);
                }
        }
#pragma unroll
        for (int m = 0; m < 2; ++m)
#pragma unroll
            for (int n = 0; n < 2; ++n) {
                const int col = wid * 32 + n * 16 + l15;
                const float bb = b1[col];
#pragma unroll
                for (int r = 0; r < 4; ++r) {
                    const int row = m * 16 + lg * 4 + r;
                    const float z = fmaxf(acc[m][n][r] + bb, 0.0f);
                    const unsigned short h = f2bf(z);
                    const int idx = row * ACT_STR + col;
                    sm[A1H + idx] = h;
                    sm[A1L + idx] = f2bf(z - bf2f(h));
                }
            }
    }
    __syncthreads();

    // GEMM2
    {
        f32x4 acc[2];
        acc[0] = (f32x4)0.0f; acc[1] = (f32x4)0.0f;
        const int bcol = wid * 16 + l15;
#pragma unroll
        for (int s = 0; s < 4; ++s) {
            bf16x8 bh, bl, ah[2], al[2];
            bh = *(const bf16x8*)&wt[WT2H + bcol * 128 + s * 32 + lg * 8];
            bl = *(const bf16x8*)&wt[WT2L + bcol * 128 + s * 32 + lg * 8];
#pragma unroll
            for (int m = 0; m < 2; ++m) {
                const int idx = (m * 16 + l15) * ACT_STR + s * 32 + lg * 8;
                ah[m] = *(const bf16x8*)&sm[A1H + idx];
                al[m] = *(const bf16x8*)&sm[A1L + idx];
            }
#pragma unroll
            for (int m = 0; m < 2; ++m) {
                acc[m] = __builtin_amdgcn_mfma_f32_16x16x32_bf16(ah[m], bh, acc[m], 0, 0, 0);
                acc[m] = __builtin_amdgcn_mfma_f32_16x16x32_bf16(ah[m], bl, acc[m], 0, 0, 0);
                acc[m] = __builtin_amdgcn_mfma_f32_16x16x32_bf16(al[m], bh, acc[m], 0, 0, 0);
            }
        }
        if (bcol < 50) {
            const float bb = b2[bcol];
#pragma unroll
            for (int m = 0; m < 2; ++m)
#pragma unroll
                for (int r = 0; r < 4; ++r) {
                    const long row = rowBase + m * 16 + lg * 4 + r;
                    out[row * 50 + bcol] = acc[m][r] + bb;
                }
        }
    }
}

// ---------------- fallback kernel: R7 verbatim (in-kernel weight conversion) ----------------
__device__ __forceinline__ void bfrag(const float* __restrict__ w, int ldw, int col, int k0,
                                      bf16x8& bh, bf16x8& bl) {
    union { unsigned u[4]; bf16x8 v; } H, L;
#pragma unroll
    for (int jj = 0; jj < 4; ++jj) {
        const float f0 = w[(k0 + 2 * jj)     * ldw + col];
        const float f1 = w[(k0 + 2 * jj + 1) * ldw + col];
        const unsigned short h0 = f2bf(f0), h1 = f2bf(f1);
        const unsigned short l0 = f2bf(f0 - bf2f(h0)), l1 = f2bf(f1 - bf2f(h1));
        H.u[jj] = (unsigned)h0 | ((unsigned)h1 << 16);
        L.u[jj] = (unsigned)l0 | ((unsigned)l1 << 16);
    }
    bh = H.v; bl = L.v;
}
__device__ __forceinline__ void bfrag50(const float* __restrict__ w, int col, int k0,
                                        bf16x8& bh, bf16x8& bl) {
    union { unsigned u[4]; bf16x8 v; } H, L;
    const bool ok = (col < 50);
#pragma unroll
    for (int jj = 0; jj < 4; ++jj) {
        const float f0 = ok ? w[(k0 + 2 * jj)     * 50 + col] : 0.0f;
        const float f1 = ok ? w[(k0 + 2 * jj + 1) * 50 + col] : 0.0f;
        const unsigned short h0 = f2bf(f0), h1 = f2bf(f1);
        const unsigned short l0 = f2bf(f0 - bf2f(h0)), l1 = f2bf(f1 - bf2f(h1));
        H.u[jj] = (unsigned)h0 | ((unsigned)h1 << 16);
        L.u[jj] = (unsigned)l0 | ((unsigned)l1 << 16);
    }
    bh = H.v; bl = L.v;
}

__global__ __launch_bounds__(256, 2)
void lddt_conv(const float* __restrict__ x,
               const float* __restrict__ ln_scale,
               const float* __restrict__ ln_bias,
               const float* __restrict__ w0,
               const float* __restrict__ b0,
               const float* __restrict__ w1,
               const float* __restrict__ b1,
               const float* __restrict__ w2,
               const float* __restrict__ b2,
               const unsigned* flag,
               float* __restrict__ out) {
    if (flag && *flag == GOODMAGIC) return;   // ws path handled output

    __shared__ __align__(16) unsigned short sm[SMU];
    const int tid  = threadIdx.x;
    const int lane = tid & 63;
    const int l15  = lane & 15;
    const int lg   = lane >> 4;
    const int wid  = tid >> 6;
    const long rowBase = (long)blockIdx.x * BM;

    ln_phase(x, ln_scale, ln_bias, sm, tid, rowBase);
    __syncthreads();

    // GEMM0
    {
        f32x4 acc[2][2];
#pragma unroll
        for (int m = 0; m < 2; ++m) { acc[m][0] = (f32x4)0.0f; acc[m][1] = (f32x4)0.0f; }
#pragma unroll
        for (int s = 0; s < 12; ++s) {
            bf16x8 bh[2], bl[2], ah[2], al[2];
#pragma unroll
            for (int n = 0; n < 2; ++n)
                bfrag(w0, 128, wid * 32 + n * 16 + l15, s * 32 + lg * 8, bh[n], bl[n]);
#pragma unroll
            for (int m = 0; m < 2; ++m) {
                const int idx = (m * 16 + l15) * A0_STR + s * 32 + lg * 8;
                ah[m] = *(const bf16x8*)&sm[A0H + idx];
                al[m] = *(const bf16x8*)&sm[A0L + idx];
            }
#pragma unroll
            for (int m = 0; m < 2; ++m)
#pragma unroll
                for (int n = 0; n < 2; ++n) {
                    acc[m][n] = __builtin_amdgcn_mfma_f32_16x16x32_bf16(ah[m], bh[n], acc[m][n], 0, 0, 0);
                    acc[m][n] = __builtin_amdgcn_mfma_f32_16x16x32_bf16(ah[m], bl[n], acc[m][n], 0, 0, 0);
                    acc[m][n] = __builtin_amdgcn_mfma_f32_16x16x32_bf16(al[m], bh[n], acc[m][n], 0, 0, 0);
                }
        }
#pragma unroll
        for (int m = 0; m < 2; ++m)
#pragma unroll
            for (int n = 0; n < 2; ++n) {
                const int col = wid * 32 + n * 16 + l15;
                const float bb = b0[col];
#pragma unroll
                for (int r = 0; r < 4; ++r) {
                    const int row = m * 16 + lg * 4 + r;
                    const float z = fmaxf(acc[m][n][r] + bb, 0.0f);
                    const unsigned short h = f2bf(z);
                    const int idx = row * ACT_STR + col;
                    sm[AC0H + idx] = h;
                    sm[AC0L + idx] = f2bf(z - bf2f(h));
                }
            }
    }
    __syncthreads();

    // GEMM1
    {
        f32x4 acc[2][2];
#pragma unroll
        for (int m = 0; m < 2; ++m) { acc[m][0] = (f32x4)0.0f; acc[m][1] = (f32x4)0.0f; }
#pragma unroll
        for (int s = 0; s < 4; ++s) {
            bf16x8 bh[2], bl[2], ah[2], al[2];
#pragma unroll
            for (int n = 0; n < 2; ++n)
                bfrag(w1, 128, wid * 32 + n * 16 + l15, s * 32 + lg * 8, bh[n], bl[n]);
#pragma unroll
            for (int m = 0; m < 2; ++m) {
                const int idx = (m * 16 + l15) * ACT_STR + s * 32 + lg * 8;
                ah[m] = *(const bf16x8*)&sm[AC0H + idx];
                al[m] = *(const bf16x8*)&sm[AC0L + idx];
            }
#pragma unroll
            for (int m = 0; m < 2; ++m)
#pragma unroll
                for (int n = 0; n < 2; ++n) {
                    acc[m][n] = __builtin_amdgcn_mfma_f32_16x16x32_bf16(ah[m], bh[n], acc[m][n], 0, 0, 0);
                    acc[m][n] = __builtin_amdgcn_mfma_f32_16x16x32_bf16(ah[m], bl[n], acc[m][n], 0, 0, 0);
                    acc[m][n] = __builtin_amdgcn_mfma_f32_16x16x32_bf16(al[m], bh[n], acc[m][n], 0, 0, 0);
                }
        }
#pragma unroll
        for (int m = 0; m < 2; ++m)
#pragma unroll
            for (int n = 0; n < 2; ++n) {
                const int col = wid * 32 + n * 16 + l15;
                const float bb = b1[col];
#pragma unroll
                for (int r = 0; r < 4; ++r) {
                    const int row = m * 16 + lg * 4 + r;
                    const float z = fmaxf(acc[m][n][r] + bb, 0.0f);
                    const unsigned short h = f2bf(z);
                    const int idx = row * ACT_STR + col;
                    sm[A1H + idx] = h;
                    sm[A1L + idx] = f2bf(z - bf2f(h));
                }
            }
    }
    __syncthreads();

    // GEMM2
    {
        f32x4 acc[2];
        acc[0] = (f32x4)0.0f; acc[1] = (f32x4)0.0f;
        const int bcol = wid * 16 + l15;
#pragma unroll
        for (int s = 0; s < 4; ++s) {
            bf16x8 bh, bl, ah[2], al[2];
            bfrag50(w2, bcol, s * 32 + lg * 8, bh, bl);
#pragma unroll
            for (int m = 0; m < 2; ++m) {
                const int idx = (m * 16 + l15) * ACT_STR + s * 32 + lg * 8;
                ah[m] = *(const bf16x8*)&sm[A1H + idx];
                al[m] = *(const bf16x8*)&sm[A1L + idx];
            }
#pragma unroll
            for (int m = 0; m < 2; ++m) {
                acc[m] = __builtin_amdgcn_mfma_f32_16x16x32_bf16(ah[m], bh, acc[m], 0, 0, 0);
                acc[m] = __builtin_amdgcn_mfma_f32_16x16x32_bf16(ah[m], bl, acc[m], 0, 0, 0);
                acc[m] = __builtin_amdgcn_mfma_f32_16x16x32_bf16(al[m], bh, acc[m], 0, 0, 0);
            }
        }
        if (bcol < 50) {
            const float bb = b2[bcol];
#pragma unroll
            for (int m = 0; m < 2; ++m)
#pragma unroll
                for (int r = 0; r < 4; ++r) {
                    const long row = rowBase + m * 16 + lg * 4 + r;
                    out[row * 50 + bcol] = acc[m][r] + bb;
                }
        }
    }
}

extern "C" void kernel_launch(void* const* d_in, const int* in_sizes, int n_in,
                              void* d_out, int out_size, void* d_ws, size_t ws_size,
                              hipStream_t stream) {
    const float* x        = (const float*)d_in[0];
    const float* ln_scale = (const float*)d_in[1];
    const float* ln_bias  = (const float*)d_in[2];
    const float* w0       = (const float*)d_in[3];
    const float* b0       = (const float*)d_in[4];
    const float* w1       = (const float*)d_in[5];
    const float* b1       = (const float*)d_in[6];
    const float* w2       = (const float*)d_in[7];
    const float* b2       = (const float*)d_in[8];
    float* out = (float*)d_out;

    const bool ws_ok = (ws_size >= WS_NEED);
    if (ws_ok) {
        unsigned* flag = (unsigned*)d_ws;
        unsigned short* wt = (unsigned short*)d_ws + 8;   // 16B flag slot
        set_flag<<<1, 64, 0, stream>>>(flag, GOODMAGIC);
        prep_weights<<<(PREP_N + 255) / 256, 256, 0, stream>>>(w0, w1, w2, wt);
        check_weights<<<(PREP_N + 255) / 256, 256, 0, stream>>>(w0, w1, w2, wt, flag);
        lddt_ws<<<NRES / BM, 256, 0, stream>>>(
            x, ln_scale, ln_bias, wt, flag, b0, b1, b2, out);
        lddt_conv<<<NRES / BM, 256, 0, stream>>>(
            x, ln_scale, ln_bias, w0, b0, w1, b1, w2, b2, flag, out);
    } else {
        lddt_conv<<<NRES / BM, 256, 0, stream>>>(
            x, ln_scale, ln_bias, w0, b0, w1, b1, w2, b2, (const unsigned*)nullptr, out);
    }
}